// Round 7
// baseline (8763.955 us; speedup 1.0000x reference)
//
#include <hip/hip_runtime.h>
#include <stdint.h>
#include <stddef.h>

// 2-layer tanh RNN, T=4096, B=32, D=H=256.
// 64 blocks x 512 threads: block = (stage, batch). Stage0 = layer0, stage1 = layer1.
// Per matvec group (256 thr): thread (cg,rg) = rows rg*4+q, cols cg*64..cg*64+63.
// Weights in VGPRs (f16x2 packed, 128 regs), operand chunk broadcast from LDS (8 x b128,
// reused over 4 rows), cross-cg reduce via LDS psum. Stage0->Stage1 h0 stream via f16
// ring in d_ws with tagged flags (poison-safe), agent-scope release/acquire.

#define TSTEPS 4096
#define NB     32
#define HD     256
#define RING_D 64      // ring depth (steps), power of 2
#define AHEAD  32      // producer max lead over consumer-published progress
#define PCHK   16      // producer backpressure check period
#define CPUB   8       // consumer progress publish period

typedef _Float16 half2_t __attribute__((ext_vector_type(2)));

#ifndef __has_builtin
#define __has_builtin(x) 0
#endif

#if __has_builtin(__builtin_amdgcn_fdot2)
#define HAVE_FDOT2 1
#endif

__device__ __forceinline__ uint32_t pack2(float a, float b) {
  half2_t h;
  h.x = (_Float16)a;
  h.y = (_Float16)b;
  return __builtin_bit_cast(uint32_t, h);
}

__device__ __forceinline__ uint16_t f16b(float f) {
  _Float16 h = (_Float16)f;
  return __builtin_bit_cast(uint16_t, h);
}

__device__ __forceinline__ float dot2acc(uint32_t a, uint32_t b, float acc) {
  half2_t ha = __builtin_bit_cast(half2_t, a);
  half2_t hb = __builtin_bit_cast(half2_t, b);
#ifdef HAVE_FDOT2
  return __builtin_amdgcn_fdot2(ha, hb, acc, false);
#else
  acc = fmaf((float)ha.x, (float)hb.x, acc);
  return fmaf((float)ha.y, (float)hb.y, acc);
#endif
}

__device__ __forceinline__ float fast_tanh(float x) {
  // tanh(x) = 1 - 2/(exp(2x)+1); exp(2x) = 2^(x * 2*log2(e)). |err| ~ 1e-6.
  x = fminf(9.0f, fmaxf(-9.0f, x));
  float t = exp2f(x * 2.8853900817779268f);
  return 1.0f - 2.0f / (t + 1.0f);
}

__global__ __launch_bounds__(512, 2) void rnn_pipe(
    const float* __restrict__ xin,
    const float* __restrict__ Wih,
    const float* __restrict__ Whh,
    const float* __restrict__ bih,
    const float* __restrict__ bhh,
    const float* __restrict__ h0in,
    float* __restrict__ out,
    uint8_t* __restrict__ ws)
{
  const int blk = blockIdx.x;
  const int st  = blk >> 5;   // 0: layer0 producer, 1: layer1 consumer
  const int b   = blk & 31;   // batch
  const int tid = threadIdx.x;
  const int g   = tid >> 8;   // 0 = input-side matvec, 1 = recurrent matvec + finish
  const int idx = tid & 255;  // index within group
  const int cg  = idx >> 6;   // column group (0..3) — uniform per wave
  const int rg  = idx & 63;   // row group (4 rows each)

  // d_ws layout: ring f16 [NB][RING_D][HD] (1MB) | flags u32 [NB][TSTEPS/4] (128KB) | cons u32 [NB]
  uint16_t* ring  = (uint16_t*)ws;
  uint32_t* flags = (uint32_t*)(ws + (size_t)NB * RING_D * HD * 2);
  uint32_t* cons  = flags + NB * (TSTEPS / 4);
  const uint32_t* ring32 = (const uint32_t*)ring;
  uint32_t* myflags = flags + (size_t)b * (TSTEPS / 4);

  // ---- load this thread's 4x64 weight tile into VGPRs as packed f16 pairs ----
  const float* mat = ((g == 0) ? Wih : Whh) + (size_t)st * HD * HD;
  uint32_t w[4][32];
#pragma unroll
  for (int q = 0; q < 4; ++q) {
    const float4* wv = (const float4*)(mat + (size_t)(rg * 4 + q) * HD + cg * 64);
#pragma unroll
    for (int i = 0; i < 16; ++i) {
      float4 v = wv[i];
      w[q][2 * i + 0] = pack2(v.x, v.y);
      w[q][2 * i + 1] = pack2(v.z, v.w);
    }
  }

  __shared__ __align__(16) uint16_t opA[HD];   // stage0: x(t); stage1: h0(t)   (f16)
  __shared__ __align__(16) uint16_t opB[HD];   // recurrent state (h0 or h1)    (f16)
  __shared__ __align__(16) float psum[2][4][64][4];  // [group][cg][rg][q] partials

  float biasreg = 0.f;
  if (g == 1) {
    biasreg = bih[st * HD + idx] + bhh[st * HD + idx];
    opB[idx] = f16b(h0in[(size_t)st * NB * HD + (size_t)b * HD + idx]);
  }

  float xr0 = 0.f, xr1 = 0.f;       // stage0: x prefetch (2 steps deep)
  uint32_t hreg0 = 0, hreg1 = 0;    // stage1: h0 stream prefetch (2 steps deep)
  int fr = -1;                      // stage1 tid511: known-published flag frontier

  if (st == 0) {
    if (g == 0) {
      xr0 = xin[((size_t)0 * NB + b) * HD + idx];
      xr1 = xin[((size_t)1 * NB + b) * HD + idx];
    }
  } else {
    if (tid == 511) {
      const int tgt = 11;  // covers prologue slots 0,1 and first steps (tgt%4==3)
      const uint32_t tag = 0x5A000000u | tgt;
      while (__hip_atomic_load(myflags + (tgt >> 2), __ATOMIC_ACQUIRE, __HIP_MEMORY_SCOPE_AGENT) != tag)
        __builtin_amdgcn_s_sleep(2);
      fr = tgt;
    }
    __syncthreads();  // spin completes before anyone loads stream data
    if (tid < 128) {
      hreg0 = __hip_atomic_load(ring32 + ((size_t)b * RING_D + 0) * 128 + tid,
                                __ATOMIC_RELAXED, __HIP_MEMORY_SCOPE_AGENT);
      hreg1 = __hip_atomic_load(ring32 + ((size_t)b * RING_D + 1) * 128 + tid,
                                __ATOMIC_RELAXED, __HIP_MEMORY_SCOPE_AGENT);
    }
  }
  __syncthreads();

  for (int t = 0; t < TSTEPS; ++t) {
    // ---------- P0: refresh operand A, flow control ----------
    if (st == 0) {
      if (g == 0) {
        opA[idx] = f16b(xr0);        // x(t)
        xr0 = xr1;
        if (t + 2 < TSTEPS)
          xr1 = xin[((size_t)(t + 2) * NB + b) * HD + idx];
      } else if (tid == 256 && (t & (PCHK - 1)) == 0 && t >= AHEAD) {
        for (;;) {  // ring WAR backpressure
          uint32_t c = __hip_atomic_load(&cons[b], __ATOMIC_RELAXED, __HIP_MEMORY_SCOPE_AGENT);
          int v = ((c >> 24) == 0x5Bu) ? (int)(c & 0xFFFFFFu) : -1;
          if (t - v <= AHEAD) break;
          __builtin_amdgcn_s_sleep(2);
        }
      }
    } else {
      if (tid < 128) {
        ((uint32_t*)opA)[tid] = hreg0;  // h0(t)
        hreg0 = hreg1;
      }
      if (tid == 511) {
        // invariant at BAR1-exit: fr >= min(t+2, T-1); flags monotone (all published idx%4==3)
        int need = t + 2; if (need > TSTEPS - 1) need = TSTEPS - 1;
        if (fr < need) {
          int tgt = (t + 9) | 3; if (tgt > TSTEPS - 1) tgt = TSTEPS - 1;
          const uint32_t tag = 0x5A000000u | (uint32_t)tgt;
          while (__hip_atomic_load(myflags + (tgt >> 2), __ATOMIC_ACQUIRE, __HIP_MEMORY_SCOPE_AGENT) != tag)
            __builtin_amdgcn_s_sleep(2);
          fr = tgt;
        }
      }
    }
    __syncthreads();  // BAR1

    // ---------- P1: dots (+ publish / stream prefetch) ----------
    if (st == 0) {
      if (tid == 256 && t > 0 && ((t - 1) & 3) == 3) {
        // ring stores for steps <= t-1 fenced at step t-1; BAR1 ordered them before this
        __hip_atomic_store(myflags + ((t - 1) >> 2), 0x5A000000u | (uint32_t)(t - 1),
                           __ATOMIC_RELEASE, __HIP_MEMORY_SCOPE_AGENT);
      }
    } else {
      if (tid < 128 && t + 2 < TSTEPS) {
        hreg1 = __hip_atomic_load(
            ring32 + ((size_t)b * RING_D + (size_t)((t + 2) & (RING_D - 1))) * 128 + tid,
            __ATOMIC_RELAXED, __HIP_MEMORY_SCOPE_AGENT);
      }
    }
    {
      const uint16_t* op = (g == 0) ? opA : opB;
      const uint4* p = (const uint4*)(op + cg * 64);  // wave-uniform address
      float a0 = 0.f, a1 = 0.f, a2 = 0.f, a3 = 0.f;
#pragma unroll
      for (int c = 0; c < 8; ++c) {
        uint4 qv = p[c];
        a0 = dot2acc(w[0][4 * c + 0], qv.x, a0);
        a1 = dot2acc(w[1][4 * c + 0], qv.x, a1);
        a2 = dot2acc(w[2][4 * c + 0], qv.x, a2);
        a3 = dot2acc(w[3][4 * c + 0], qv.x, a3);
        a0 = dot2acc(w[0][4 * c + 1], qv.y, a0);
        a1 = dot2acc(w[1][4 * c + 1], qv.y, a1);
        a2 = dot2acc(w[2][4 * c + 1], qv.y, a2);
        a3 = dot2acc(w[3][4 * c + 1], qv.y, a3);
        a0 = dot2acc(w[0][4 * c + 2], qv.z, a0);
        a1 = dot2acc(w[1][4 * c + 2], qv.z, a1);
        a2 = dot2acc(w[2][4 * c + 2], qv.z, a2);
        a3 = dot2acc(w[3][4 * c + 2], qv.z, a3);
        a0 = dot2acc(w[0][4 * c + 3], qv.w, a0);
        a1 = dot2acc(w[1][4 * c + 3], qv.w, a1);
        a2 = dot2acc(w[2][4 * c + 3], qv.w, a2);
        a3 = dot2acc(w[3][4 * c + 3], qv.w, a3);
      }
      float4 acc4;
      acc4.x = a0; acc4.y = a1; acc4.z = a2; acc4.w = a3;
      *(float4*)(&psum[g][cg][rg][0]) = acc4;  // coalesced b128 store
    }
    __syncthreads();  // BAR2

    // ---------- P2: combine, tanh, state update, stream/output ----------
    if (g == 1) {
      const int r2 = idx >> 2, q2 = idx & 3;
      float s = biasreg;
#pragma unroll
      for (int c = 0; c < 4; ++c) s += psum[0][c][r2][q2] + psum[1][c][r2][q2];
      float h = fast_tanh(s);
      uint16_t hb = f16b(h);
      opB[idx] = hb;  // recurrent state for next step
      if (st == 0) {
        ring[((size_t)b * RING_D + (t & (RING_D - 1))) * HD + idx] = hb;
        if ((t & 3) == 3) __threadfence();  // ring stores agent-visible before flag publish
      } else {
        out[((size_t)t * NB + b) * HD + idx] = h;
        if (tid == 256 && (t & (CPUB - 1)) == (CPUB - 1))
          __hip_atomic_store(&cons[b], 0x5B000000u | (uint32_t)t,
                             __ATOMIC_RELAXED, __HIP_MEMORY_SCOPE_AGENT);
      }
    }
    // next iteration's BAR1 separates P2 writes from P1 reads
  }

  // epilogue: publish final flag (covers tail steps off the mod-4 publish grid)
  if (st == 0) {
    if (g == 1) __threadfence();
    __syncthreads();
    if (tid == 256)
      __hip_atomic_store(myflags + ((TSTEPS - 1) >> 2), 0x5A000000u | (uint32_t)(TSTEPS - 1),
                         __ATOMIC_RELEASE, __HIP_MEMORY_SCOPE_AGENT);
  }
}

extern "C" void kernel_launch(void* const* d_in, const int* in_sizes, int n_in,
                              void* d_out, int out_size, void* d_ws, size_t ws_size,
                              hipStream_t stream) {
  const float* x   = (const float*)d_in[0];
  const float* Wih = (const float*)d_in[1];
  const float* Whh = (const float*)d_in[2];
  const float* bih = (const float*)d_in[3];
  const float* bhh = (const float*)d_in[4];
  const float* h0  = (const float*)d_in[5];
  float* out = (float*)d_out;
  (void)in_sizes; (void)n_in; (void)out_size; (void)ws_size;
  rnn_pipe<<<dim3(64), dim3(512), 0, stream>>>(x, Wih, Whh, bih, bhh, h0, out, (uint8_t*)d_ws);
}

// Round 8
// 6015.249 us; speedup vs baseline: 1.4570x; 1.4570x over previous
//
#include <hip/hip_runtime.h>
#include <stdint.h>
#include <stddef.h>

// 2-layer tanh RNN, T=4096, B=32, D=H=256. Two kernels:
//  1) pre_gemm (throughput, 2048 blocks): pre[t,b,:] = Wih0·x[t,b,:] + bih0 + bhh0,
//     written f32 into d_out (read-ahead in the sequential kernel is always >= 2
//     positions ahead of its own writes, so in-place is race-free).
//  2) rnn_seq (latency, 32 blocks = 1/batch, 512 thr): per step
//     A: G0 Whh0·h0(t-1), G1 Whh1·h1(t-1)   (concurrent, weights in VGPRs)
//     B: G0 finishes h0(t) = tanh(pre[t] + A0)
//     C: all 512 threads: Wih1·h0(t)        (64 u32 weights/thread)
//     D: G1 finishes h1(t) = tanh(C + A1 + b1), stores to d_out.
// No cross-block sync of any kind.

#define TSTEPS 4096
#define NB     32
#define HD     256
#define PPB    64   // pairs per prepass block

typedef _Float16 half2_t __attribute__((ext_vector_type(2)));

#ifndef __has_builtin
#define __has_builtin(x) 0
#endif
#if __has_builtin(__builtin_amdgcn_fdot2)
#define HAVE_FDOT2 1
#endif

__device__ __forceinline__ uint32_t pack2(float a, float b) {
  half2_t h; h.x = (_Float16)a; h.y = (_Float16)b;
  return __builtin_bit_cast(uint32_t, h);
}
__device__ __forceinline__ uint16_t f16b(float f) {
  _Float16 h = (_Float16)f; return __builtin_bit_cast(uint16_t, h);
}
__device__ __forceinline__ float dot2acc(uint32_t a, uint32_t b, float acc) {
  half2_t ha = __builtin_bit_cast(half2_t, a);
  half2_t hb = __builtin_bit_cast(half2_t, b);
#ifdef HAVE_FDOT2
  return __builtin_amdgcn_fdot2(ha, hb, acc, false);
#else
  acc = fmaf((float)ha.x, (float)hb.x, acc);
  return fmaf((float)ha.y, (float)hb.y, acc);
#endif
}
__device__ __forceinline__ float fast_tanh(float x) {
  x = fminf(9.0f, fmaxf(-9.0f, x));
  float t = exp2f(x * 2.8853900817779268f);
  return 1.0f - 2.0f / (t + 1.0f);
}

// 4-row x 64-col dot against a broadcast LDS chunk. w[q] = row q's 64 cols (32 u32).
__device__ __forceinline__ float4 dot4row(const uint32_t (&w)[4][32], const uint16_t* op) {
  const uint4* p = (const uint4*)op;
  float a0 = 0.f, a1 = 0.f, a2 = 0.f, a3 = 0.f;
#pragma unroll
  for (int c = 0; c < 8; ++c) {
    uint4 qv = p[c];
    a0 = dot2acc(w[0][4*c+0], qv.x, a0); a1 = dot2acc(w[1][4*c+0], qv.x, a1);
    a2 = dot2acc(w[2][4*c+0], qv.x, a2); a3 = dot2acc(w[3][4*c+0], qv.x, a3);
    a0 = dot2acc(w[0][4*c+1], qv.y, a0); a1 = dot2acc(w[1][4*c+1], qv.y, a1);
    a2 = dot2acc(w[2][4*c+1], qv.y, a2); a3 = dot2acc(w[3][4*c+1], qv.y, a3);
    a0 = dot2acc(w[0][4*c+2], qv.z, a0); a1 = dot2acc(w[1][4*c+2], qv.z, a1);
    a2 = dot2acc(w[2][4*c+2], qv.z, a2); a3 = dot2acc(w[3][4*c+2], qv.z, a3);
    a0 = dot2acc(w[0][4*c+3], qv.w, a0); a1 = dot2acc(w[1][4*c+3], qv.w, a1);
    a2 = dot2acc(w[2][4*c+3], qv.w, a2); a3 = dot2acc(w[3][4*c+3], qv.w, a3);
  }
  return make_float4(a0, a1, a2, a3);
}

// ---------------- prepass: pre = x @ Wih0^T + bih0 + bhh0 (f32, into d_out) -------------
__global__ __launch_bounds__(256, 2) void pre_gemm(
    const float* __restrict__ xin, const float* __restrict__ Wih,
    const float* __restrict__ bih, const float* __restrict__ bhh,
    float* __restrict__ pre)
{
  const int idx = threadIdx.x;
  const int cg = idx >> 6, rg = idx & 63;

  uint32_t w[4][32];
#pragma unroll
  for (int q = 0; q < 4; ++q) {
    const float4* wv = (const float4*)(Wih + (size_t)(rg * 4 + q) * HD + (cg << 6));
#pragma unroll
    for (int i = 0; i < 16; ++i) {
      float4 v = wv[i];
      w[q][2*i] = pack2(v.x, v.y); w[q][2*i+1] = pack2(v.z, v.w);
    }
  }

  __shared__ __align__(16) uint16_t opA[HD];
  __shared__ __align__(16) float psum[4][64][4];
  const float bias = bih[idx] + bhh[idx];

  const size_t p0 = (size_t)blockIdx.x * PPB;
  opA[idx] = f16b(xin[p0 * HD + idx]);
  __syncthreads();

  for (int k = 0; k < PPB; ++k) {
    float xnext = 0.f;
    if (k + 1 < PPB) xnext = xin[(p0 + k + 1) * HD + idx];  // issue early
    float4 a = dot4row(w, opA + (cg << 6));
    *(float4*)&psum[cg][rg][0] = a;
    __syncthreads();
    float s = bias;
#pragma unroll
    for (int c = 0; c < 4; ++c) s += psum[c][idx >> 2][idx & 3];
    pre[(p0 + k) * HD + idx] = s;
    if (k + 1 < PPB) opA[idx] = f16b(xnext);  // dots all done before prev barrier
    __syncthreads();
  }
}

// ---------------- sequential RNN: 1 block per batch, zero cross-block sync -------------
__global__ __launch_bounds__(512, 2) void rnn_seq(
    const float* __restrict__ Wih,   // layer 1 used
    const float* __restrict__ Whh,   // layers 0,1
    const float* __restrict__ bih, const float* __restrict__ bhh,
    const float* __restrict__ h0in,
    float* __restrict__ io)          // pre in (from pre_gemm), h1 out
{
  const int b   = blockIdx.x;
  const int tid = threadIdx.x;
  const int g   = tid >> 8;          // 0: layer0 recurrent, 1: layer1 recurrent
  const int idx = tid & 255;
  const int cg  = idx >> 6, rg = idx & 63;   // primary tile coords (wave-uniform cg)
  const int c2  = tid >> 7;                  // 0..3, wave-uniform (phase C)
  const int r2  = tid & 127;                 // phase C row-pair index

  // primary recurrent matrix (Whh layer g): rows rg*4+q, cols cg*64.. (128 u32)
  uint32_t w[4][32];
  {
    const float* mat = Whh + (size_t)g * HD * HD;
#pragma unroll
    for (int q = 0; q < 4; ++q) {
      const float4* wv = (const float4*)(mat + (size_t)(rg * 4 + q) * HD + (cg << 6));
#pragma unroll
      for (int i = 0; i < 16; ++i) {
        float4 v = wv[i];
        w[q][2*i] = pack2(v.x, v.y); w[q][2*i+1] = pack2(v.z, v.w);
      }
    }
  }
  // Wih layer 1: rows r2*2+q, cols c2*64.. (64 u32, spread over all 512 threads)
  uint32_t w1[2][32];
  {
    const float* m1 = Wih + (size_t)HD * HD;
#pragma unroll
    for (int q = 0; q < 2; ++q) {
      const float4* wv = (const float4*)(m1 + (size_t)(r2 * 2 + q) * HD + (c2 << 6));
#pragma unroll
      for (int i = 0; i < 16; ++i) {
        float4 v = wv[i];
        w1[q][2*i] = pack2(v.x, v.y); w1[q][2*i+1] = pack2(v.z, v.w);
      }
    }
  }

  __shared__ __align__(16) uint16_t hA[HD];         // h0 state (f16)
  __shared__ __align__(16) uint16_t hB[HD];         // h1 state (f16)
  __shared__ __align__(16) float psum0[4][64][4];   // layer0 recurrent partials
  __shared__ __align__(16) float psum1[4][64][4];   // layer1 recurrent partials
  __shared__ __align__(16) float2 psumC[4][128];    // Wih1·h0(t) partials

  float bias1 = 0.f;
  if (g == 1) bias1 = bih[HD + idx] + bhh[HD + idx];
  if (g == 0) hA[idx] = f16b(h0in[(size_t)b * HD + idx]);
  else        hB[idx] = f16b(h0in[(size_t)(NB + b) * HD + idx]);

  float pr0 = 0.f, pr1 = 0.f;  // pre[t], pre[t+1] (G0 threads)
  if (g == 0) {
    pr0 = io[((size_t)0 * NB + b) * HD + idx];
    pr1 = io[((size_t)1 * NB + b) * HD + idx];
  }
  __syncthreads();

  for (int t = 0; t < TSTEPS; ++t) {
    // ---- phase A: recurrent matvecs (both layers concurrently) + pre prefetch ----
    float prn = 0.f;
    if (g == 0 && t + 2 < TSTEPS)
      prn = io[((size_t)(t + 2) * NB + b) * HD + idx];
    {
      const uint16_t* op = (g == 0) ? hA : hB;
      float4 a = dot4row(w, op + (cg << 6));
      if (g == 0) *(float4*)&psum0[cg][rg][0] = a;
      else        *(float4*)&psum1[cg][rg][0] = a;
    }
    __syncthreads();  // BAR1

    // ---- phase B: finish h0(t) (G0 only) ----
    if (g == 0) {
      float s = pr0;
#pragma unroll
      for (int c = 0; c < 4; ++c) s += psum0[c][idx >> 2][idx & 3];
      hA[idx] = f16b(fast_tanh(s));
      pr0 = pr1; pr1 = prn;
    }
    __syncthreads();  // BAR2

    // ---- phase C: Wih1·h0(t), all 512 threads ----
    {
      const uint4* pc = (const uint4*)(hA + (c2 << 6));  // wave-uniform chunk
      float b00 = 0.f, b01 = 0.f, b10 = 0.f, b11 = 0.f;
#pragma unroll
      for (int c = 0; c < 4; ++c) {
        uint4 q0 = pc[2*c], q1 = pc[2*c+1];
        b00 = dot2acc(w1[0][8*c+0], q0.x, b00); b10 = dot2acc(w1[1][8*c+0], q0.x, b10);
        b00 = dot2acc(w1[0][8*c+1], q0.y, b00); b10 = dot2acc(w1[1][8*c+1], q0.y, b10);
        b00 = dot2acc(w1[0][8*c+2], q0.z, b00); b10 = dot2acc(w1[1][8*c+2], q0.z, b10);
        b00 = dot2acc(w1[0][8*c+3], q0.w, b00); b10 = dot2acc(w1[1][8*c+3], q0.w, b10);
        b01 = dot2acc(w1[0][8*c+4], q1.x, b01); b11 = dot2acc(w1[1][8*c+4], q1.x, b11);
        b01 = dot2acc(w1[0][8*c+5], q1.y, b01); b11 = dot2acc(w1[1][8*c+5], q1.y, b11);
        b01 = dot2acc(w1[0][8*c+6], q1.z, b01); b11 = dot2acc(w1[1][8*c+6], q1.z, b11);
        b01 = dot2acc(w1[0][8*c+7], q1.w, b01); b11 = dot2acc(w1[1][8*c+7], q1.w, b11);
      }
      psumC[c2][r2] = make_float2(b00 + b01, b10 + b11);
    }
    __syncthreads();  // BAR3

    // ---- phase D: finish h1(t) (G1 only), store output ----
    if (g == 1) {
      float s = bias1;
#pragma unroll
      for (int c = 0; c < 4; ++c) s += psum1[c][idx >> 2][idx & 3];
#pragma unroll
      for (int c = 0; c < 4; ++c) s += ((const float*)&psumC[c][idx >> 1])[idx & 1];
      float h = fast_tanh(s);
      hB[idx] = f16b(h);
      io[((size_t)t * NB + b) * HD + idx] = h;
    }
    __syncthreads();  // BAR4 (hB ready for next phase A)
  }
}

extern "C" void kernel_launch(void* const* d_in, const int* in_sizes, int n_in,
                              void* d_out, int out_size, void* d_ws, size_t ws_size,
                              hipStream_t stream) {
  const float* x   = (const float*)d_in[0];
  const float* Wih = (const float*)d_in[1];
  const float* Whh = (const float*)d_in[2];
  const float* bih = (const float*)d_in[3];
  const float* bhh = (const float*)d_in[4];
  const float* h0  = (const float*)d_in[5];
  float* out = (float*)d_out;
  (void)in_sizes; (void)n_in; (void)out_size; (void)d_ws; (void)ws_size;
  pre_gemm<<<dim3((TSTEPS * NB) / PPB), dim3(256), 0, stream>>>(x, Wih, bih, bhh, out);
  rnn_seq<<<dim3(NB), dim3(512), 0, stream>>>(Wih, Whh, bih, bhh, h0, out);
}